// Round 6
// baseline (193.512 us; speedup 1.0000x reference)
//
#include <hip/hip_runtime.h>

#define D 128
#define NXCD 8

typedef __attribute__((ext_vector_type(8))) short bf16x8;
typedef __attribute__((ext_vector_type(4))) float f32x4;

__device__ __forceinline__ unsigned short f2bf(float f) {
  unsigned int u = __float_as_uint(f);
  u = (u + 0x7fffu + ((u >> 16) & 1)) >> 16;
  return (unsigned short)u;
}

// ---------------------------------------------------------------------------
// Pass 0: convert h (f32) -> h16 (bf16, RNE).  4 elements / thread.
// ---------------------------------------------------------------------------
__global__ __launch_bounds__(256) void cvt_kernel(
    const float* __restrict__ h, unsigned short* __restrict__ h16, int total4) {
  int i = blockIdx.x * blockDim.x + threadIdx.x;
  if (i >= total4) return;
  float4 v = ((const float4*)h)[i];
  ushort4 o;
  o.x = f2bf(v.x); o.y = f2bf(v.y); o.z = f2bf(v.z); o.w = f2bf(v.w);
  ((ushort4*)h16)[i] = o;
}

// ---------------------------------------------------------------------------
// Pass A: histogram into per-XCD plane: deg8[(bid&7)*N + dst].
// Same edge->block map as scatter_kernel (4 edges/thread, 256 thr/block).
// ---------------------------------------------------------------------------
__global__ __launch_bounds__(256) void hist_kernel(
    const int* __restrict__ edst, int* __restrict__ deg8, int E, int N) {
  int plane = (blockIdx.x & (NXCD - 1)) * N;
  int i = (blockIdx.x * blockDim.x + threadIdx.x) * 4;
  if (i + 4 <= E) {
    int4 d = *(const int4*)(edst + i);
    atomicAdd(deg8 + plane + d.x, 1);
    atomicAdd(deg8 + plane + d.y, 1);
    atomicAdd(deg8 + plane + d.z, 1);
    atomicAdd(deg8 + plane + d.w, 1);
  } else {
    for (int k = i; k < E; ++k) atomicAdd(deg8 + plane + edst[k], 1);
  }
}

// ---------------------------------------------------------------------------
// Pass B1: 512-element chunk sums of deg8 (total = 8N) -> bsum[b]
// ---------------------------------------------------------------------------
__global__ __launch_bounds__(256) void scan_reduce_kernel(
    const int* __restrict__ deg, int* __restrict__ bsum, int total) {
  __shared__ int ts[256];
  int t = threadIdx.x;
  int base = blockIdx.x * 512 + 2 * t;
  int e0 = (base < total) ? deg[base] : 0;
  int e1 = (base + 1 < total) ? deg[base + 1] : 0;
  ts[t] = e0 + e1;
  __syncthreads();
  for (int off = 128; off > 0; off >>= 1) {
    if (t < off) ts[t] += ts[t + off];
    __syncthreads();
  }
  if (t == 0) bsum[blockIdx.x] = ts[0];
}

// ---------------------------------------------------------------------------
// Pass B2: single 1024-thread block scans block sums (nb <= 1024) -> excl boff
// ---------------------------------------------------------------------------
__global__ __launch_bounds__(1024) void scan_blocksums_kernel(
    const int* __restrict__ bsum, int* __restrict__ boff, int nb) {
  __shared__ int ts[1024];
  int t = threadIdx.x;
  ts[t] = (t < nb) ? bsum[t] : 0;
  __syncthreads();
  for (int off = 1; off < 1024; off <<= 1) {
    int v = (t >= off) ? ts[t - off] : 0;
    __syncthreads();
    ts[t] += v;
    __syncthreads();
  }
  if (t < nb) boff[t] = (t == 0) ? 0 : ts[t - 1];
}

// ---------------------------------------------------------------------------
// Pass B3: per-block 512-element exclusive scan + block offset -> cur8
// ---------------------------------------------------------------------------
__global__ __launch_bounds__(256) void scan_final_kernel(
    const int* __restrict__ deg, const int* __restrict__ boff,
    int* __restrict__ cur, int total) {
  __shared__ int ts[256];
  int t = threadIdx.x;
  int base = blockIdx.x * 512 + 2 * t;
  int e0 = (base < total) ? deg[base] : 0;
  int e1 = (base + 1 < total) ? deg[base + 1] : 0;
  ts[t] = e0 + e1;
  __syncthreads();
  for (int off = 1; off < 256; off <<= 1) {
    int x = (t >= off) ? ts[t - off] : 0;
    __syncthreads();
    ts[t] += x;
    __syncthreads();
  }
  int excl = ((t > 0) ? ts[t - 1] : 0) + boff[blockIdx.x];
  if (base < total) cur[base] = excl;
  if (base + 1 < total) cur[base + 1] = excl + e0;
}

// ---------------------------------------------------------------------------
// Pass C: scatter edges into the (bid&7) plane's buckets.  Atomics and
// record lines are XCD-local (no cross-XCD line bounce).  Atomics issued
// 4-deep before the dependent stores.
// ---------------------------------------------------------------------------
__global__ __launch_bounds__(256) void scatter_kernel(
    const float* __restrict__ alpha, const float* __restrict__ ew,
    const int* __restrict__ node_id, const int* __restrict__ esrc,
    const int* __restrict__ edst, int* __restrict__ cur8,
    int2* __restrict__ recs, int E, int gene_num, int N) {
  int plane = (blockIdx.x & (NXCD - 1)) * N;
  int i = (blockIdx.x * blockDim.x + threadIdx.x) * 4;
  if (i >= E) return;
  if (i + 4 <= E) {
    int4 s4 = *(const int4*)(esrc + i);
    int4 d4 = *(const int4*)(edst + i);
    float4 w4 = *(const float4*)(ew + i);
    int ss[4] = {s4.x, s4.y, s4.z, s4.w};
    int dd[4] = {d4.x, d4.y, d4.z, d4.w};
    float ww[4] = {w4.x, w4.y, w4.z, w4.w};
    float cf[4];
#pragma unroll
    for (int k = 0; k < 4; ++k) {
      int sid = node_id[ss[k]];
      int did = node_id[dd[k]];
      int idx;
      if (sid >= 0) idx = (did >= 0) ? gene_num : sid;
      else          idx = (did >= 0) ? did : (gene_num + 1);
      cf[k] = alpha[idx] * ww[k];
    }
    int pos[4];
#pragma unroll
    for (int k = 0; k < 4; ++k) pos[k] = atomicAdd(cur8 + plane + dd[k], 1);
#pragma unroll
    for (int k = 0; k < 4; ++k)
      recs[pos[k]] = make_int2(ss[k], __float_as_int(cf[k]));
  } else {
    for (int k = i; k < E; ++k) {
      int src = esrc[k], dst = edst[k];
      int sid = node_id[src], did = node_id[dst];
      int idx;
      if (sid >= 0) idx = (did >= 0) ? gene_num : sid;
      else          idx = (did >= 0) ? did : (gene_num + 1);
      float coeff = alpha[idx] * ew[k];
      int pos = atomicAdd(cur8 + plane + dst, 1);
      recs[pos] = make_int2(src, __float_as_int(coeff));
    }
  }
}

// ---------------------------------------------------------------------------
// Pass D: one wave per dst node.  Lane l owns bf16 pair (dims 2l,2l+1).
// Sub-buckets: lane x<8 holds {end,len} of plane x (end = cur8 after
// scatter = start+len).  Loop 8 planes, shfl-broadcast bounds, then the
// 4-deep unrolled gather pipeline.  f32 accumulate; mean row -> d_out.
// ---------------------------------------------------------------------------
__global__ __launch_bounds__(256) void accumulate_kernel(
    const unsigned short* __restrict__ h16, const int2* __restrict__ recs,
    const int* __restrict__ cur8, const int* __restrict__ deg8,
    float* __restrict__ neigh, int N) {
  int wid = (blockIdx.x * blockDim.x + threadIdx.x) >> 6;
  int l = threadIdx.x & 63;
  if (wid >= N) return;
  int endv = 0, lenv = 0;
  if (l < NXCD) {
    endv = cur8[l * N + wid];
    lenv = deg8[l * N + wid];
  }
  float ax = 0.f, ay = 0.f;
  int deg_tot = 0;
  const unsigned int* hp = ((const unsigned int*)h16) + l;  // row = 64 uints

  for (int x = 0; x < NXCD; ++x) {
    int n = __shfl(lenv, x);
    int s = __shfl(endv, x) - n;
    deg_tot += n;
    for (int i = s; i < s + n; i += 64) {
      int m = s + n - i;
      if (m > 64) m = 64;
      int2 r = make_int2(0, 0);
      if (l < m) r = recs[i + l];
      int k = 0;
      for (; k + 4 <= m; k += 4) {
        int s0 = __shfl(r.x, k + 0), s1 = __shfl(r.x, k + 1);
        int s2 = __shfl(r.x, k + 2), s3 = __shfl(r.x, k + 3);
        float c0 = __int_as_float(__shfl(r.y, k + 0));
        float c1 = __int_as_float(__shfl(r.y, k + 1));
        float c2 = __int_as_float(__shfl(r.y, k + 2));
        float c3 = __int_as_float(__shfl(r.y, k + 3));
        unsigned int v0 = hp[(size_t)s0 * 64];
        unsigned int v1 = hp[(size_t)s1 * 64];
        unsigned int v2 = hp[(size_t)s2 * 64];
        unsigned int v3 = hp[(size_t)s3 * 64];
        ax += c0 * __uint_as_float(v0 << 16);
        ay += c0 * __uint_as_float(v0 & 0xffff0000u);
        ax += c1 * __uint_as_float(v1 << 16);
        ay += c1 * __uint_as_float(v1 & 0xffff0000u);
        ax += c2 * __uint_as_float(v2 << 16);
        ay += c2 * __uint_as_float(v2 & 0xffff0000u);
        ax += c3 * __uint_as_float(v3 << 16);
        ay += c3 * __uint_as_float(v3 & 0xffff0000u);
      }
      for (; k < m; ++k) {
        int s0 = __shfl(r.x, k);
        float cf = __int_as_float(__shfl(r.y, k));
        unsigned int v = hp[(size_t)s0 * 64];
        ax += cf * __uint_as_float(v << 16);
        ay += cf * __uint_as_float(v & 0xffff0000u);
      }
    }
  }
  float inv = 1.0f / (float)(deg_tot > 0 ? deg_tot : 1);
  ((float2*)neigh)[(size_t)wid * (D / 2) + l] = make_float2(ax * inv, ay * inv);
}

// ---------------------------------------------------------------------------
// MLP (MFMA): io = relu(io @ W.T + b), in place on d_out.  (unchanged)
// ---------------------------------------------------------------------------
__global__ __launch_bounds__(256) void mlp_mfma_kernel(
    const float* __restrict__ W, const float* __restrict__ bias,
    float* __restrict__ io, int N) {
  __shared__ __align__(16) unsigned short Wl[128 * 128];  // 32 KB bf16

  int t = threadIdx.x;
#pragma unroll
  for (int i = 0; i < 8; ++i) {
    int chunk = t + 256 * i;
    int row = chunk >> 4;
    int cb = chunk & 15;
    const float* gp = W + (size_t)row * 128 + cb * 8;
    float4 a = *(const float4*)gp;
    float4 b = *(const float4*)(gp + 4);
    bf16x8 v;
    v[0] = (short)f2bf(a.x); v[1] = (short)f2bf(a.y);
    v[2] = (short)f2bf(a.z); v[3] = (short)f2bf(a.w);
    v[4] = (short)f2bf(b.x); v[5] = (short)f2bf(b.y);
    v[6] = (short)f2bf(b.z); v[7] = (short)f2bf(b.w);
    *(bf16x8*)((char*)Wl + row * 256 + ((cb ^ (row & 7)) << 4)) = v;
  }
  __syncthreads();

  int l = t & 63;
  int w = t >> 6;
  int kg = l >> 4;
  int m_base = blockIdx.x * 64 + w * 16;
  int arow = m_base + (l & 15);
  if (arow >= N) arow = N - 1;

  bf16x8 af[4];
  const float* ap = io + (size_t)arow * 128 + kg * 8;
#pragma unroll
  for (int kk = 0; kk < 4; ++kk) {
    float4 a = *(const float4*)(ap + kk * 32);
    float4 b = *(const float4*)(ap + kk * 32 + 4);
    bf16x8 v;
    v[0] = (short)f2bf(a.x); v[1] = (short)f2bf(a.y);
    v[2] = (short)f2bf(a.z); v[3] = (short)f2bf(a.w);
    v[4] = (short)f2bf(b.x); v[5] = (short)f2bf(b.y);
    v[6] = (short)f2bf(b.z); v[7] = (short)f2bf(b.w);
    af[kk] = v;
  }

#pragma unroll
  for (int c = 0; c < 8; ++c) {
    f32x4 acc = {0.f, 0.f, 0.f, 0.f};
    int row_w = c * 16 + (l & 15);
    int rs = row_w & 7;
#pragma unroll
    for (int kk = 0; kk < 4; ++kk) {
      int cb = kk * 4 + kg;
      bf16x8 bf = *(bf16x8*)((char*)Wl + row_w * 256 + ((cb ^ rs) << 4));
      acc = __builtin_amdgcn_mfma_f32_16x16x32_bf16(af[kk], bf, acc, 0, 0, 0);
    }
    int j = c * 16 + (l & 15);
    float bj = bias[j];
#pragma unroll
    for (int r = 0; r < 4; ++r) {
      int m = m_base + kg * 4 + r;
      if (m < N) io[(size_t)m * 128 + j] = fmaxf(acc[r] + bj, 0.0f);
    }
  }
}

extern "C" void kernel_launch(void* const* d_in, const int* in_sizes, int n_in,
                              void* d_out, int out_size, void* d_ws, size_t ws_size,
                              hipStream_t stream) {
  const float* h     = (const float*)d_in[0];
  const float* alpha = (const float*)d_in[1];
  const float* ew    = (const float*)d_in[2];
  const float* W     = (const float*)d_in[3];
  const float* bias  = (const float*)d_in[4];
  const int* node_id = (const int*)d_in[5];
  const int* esrc    = (const int*)d_in[6];
  const int* edst    = (const int*)d_in[7];
  float* out = (float*)d_out;

  int E = in_sizes[2];
  int N = in_sizes[5];
  int gene_num = in_sizes[1] - 2;
  int total8 = NXCD * N;                 // 400K counters
  int nbs = (total8 + 511) / 512;        // scan blocks (<=1024)

  // workspace layout
  int* deg8 = (int*)d_ws;                       // 8N
  int* cur8 = deg8 + total8;                    // 8N
  int* bsum = cur8 + total8;                    // 1024
  int* boff = bsum + 1024;                      // 1024
  size_t h16_off = (((size_t)(2 * total8) + 2048) * sizeof(int) + 15) & ~(size_t)15;
  unsigned short* h16 = (unsigned short*)((char*)d_ws + h16_off);  // N*D bf16
  size_t rec_off = (h16_off + (size_t)N * D * sizeof(unsigned short) + 15) & ~(size_t)15;
  int2* recs = (int2*)((char*)d_ws + rec_off);  // E * 8B
  size_t need = rec_off + (size_t)E * sizeof(int2);
  if (ws_size < need) return;

  hipMemsetAsync(deg8, 0, (size_t)total8 * sizeof(int), stream);

  {
    int total4 = N * D / 4;
    cvt_kernel<<<(total4 + 255) / 256, 256, 0, stream>>>(h, h16, total4);
  }
  int eblocks = (E / 4 + 255) / 256 + 1;   // MUST match between hist & scatter
  hist_kernel<<<eblocks, 256, 0, stream>>>(edst, deg8, E, N);
  scan_reduce_kernel<<<nbs, 256, 0, stream>>>(deg8, bsum, total8);
  scan_blocksums_kernel<<<1, 1024, 0, stream>>>(bsum, boff, nbs);
  scan_final_kernel<<<nbs, 256, 0, stream>>>(deg8, boff, cur8, total8);
  scatter_kernel<<<eblocks, 256, 0, stream>>>(alpha, ew, node_id, esrc, edst,
                                              cur8, recs, E, gene_num, N);
  {
    long long total = (long long)N * 64;
    int blocks = (int)((total + 255) / 256);
    accumulate_kernel<<<blocks, 256, 0, stream>>>(h16, recs, cur8, deg8, out, N);
  }
  {
    int blocks = (N + 63) / 64;
    mlp_mfma_kernel<<<blocks, 256, 0, stream>>>(W, bias, out, N);
  }
}

// Round 7
// 165.022 us; speedup vs baseline: 1.1726x; 1.1726x over previous
//
#include <hip/hip_runtime.h>

#define D 128
#define NXCD 8

typedef __attribute__((ext_vector_type(8))) short bf16x8;
typedef __attribute__((ext_vector_type(4))) float f32x4;

__device__ __forceinline__ unsigned short f2bf(float f) {
  unsigned int u = __float_as_uint(f);
  u = (u + 0x7fffu + ((u >> 16) & 1)) >> 16;
  return (unsigned short)u;
}

// ---------------------------------------------------------------------------
// Pass 0: convert h (f32) -> h16 (bf16, RNE).  4 elements / thread.
// ---------------------------------------------------------------------------
__global__ __launch_bounds__(256) void cvt_kernel(
    const float* __restrict__ h, unsigned short* __restrict__ h16, int total4) {
  int i = blockIdx.x * blockDim.x + threadIdx.x;
  if (i >= total4) return;
  float4 v = ((const float4*)h)[i];
  ushort4 o;
  o.x = f2bf(v.x); o.y = f2bf(v.y); o.z = f2bf(v.z); o.w = f2bf(v.w);
  ((ushort4*)h16)[i] = o;
}

// ---------------------------------------------------------------------------
// Pass A: histogram into per-XCD plane: deg8[(bid&7)*N + dst].
// Same edge->block map as scatter_kernel (4 edges/thread, 256 thr/block).
// ---------------------------------------------------------------------------
__global__ __launch_bounds__(256) void hist_kernel(
    const int* __restrict__ edst, int* __restrict__ deg8, int E, int N) {
  int plane = (blockIdx.x & (NXCD - 1)) * N;
  int i = (blockIdx.x * blockDim.x + threadIdx.x) * 4;
  if (i + 4 <= E) {
    int4 d = *(const int4*)(edst + i);
    atomicAdd(deg8 + plane + d.x, 1);
    atomicAdd(deg8 + plane + d.y, 1);
    atomicAdd(deg8 + plane + d.z, 1);
    atomicAdd(deg8 + plane + d.w, 1);
  } else {
    for (int k = i; k < E; ++k) atomicAdd(deg8 + plane + edst[k], 1);
  }
}

// ---------------------------------------------------------------------------
// Pass B1: 512-element chunk sums of deg8 (total = 8N) -> bsum[b]
// ---------------------------------------------------------------------------
__global__ __launch_bounds__(256) void scan_reduce_kernel(
    const int* __restrict__ deg, int* __restrict__ bsum, int total) {
  __shared__ int ts[256];
  int t = threadIdx.x;
  int base = blockIdx.x * 512 + 2 * t;
  int e0 = (base < total) ? deg[base] : 0;
  int e1 = (base + 1 < total) ? deg[base + 1] : 0;
  ts[t] = e0 + e1;
  __syncthreads();
  for (int off = 128; off > 0; off >>= 1) {
    if (t < off) ts[t] += ts[t + off];
    __syncthreads();
  }
  if (t == 0) bsum[blockIdx.x] = ts[0];
}

// ---------------------------------------------------------------------------
// Pass B2: single 1024-thread block scans block sums (nb <= 1024) -> excl boff
// ---------------------------------------------------------------------------
__global__ __launch_bounds__(1024) void scan_blocksums_kernel(
    const int* __restrict__ bsum, int* __restrict__ boff, int nb) {
  __shared__ int ts[1024];
  int t = threadIdx.x;
  ts[t] = (t < nb) ? bsum[t] : 0;
  __syncthreads();
  for (int off = 1; off < 1024; off <<= 1) {
    int v = (t >= off) ? ts[t - off] : 0;
    __syncthreads();
    ts[t] += v;
    __syncthreads();
  }
  if (t < nb) boff[t] = (t == 0) ? 0 : ts[t - 1];
}

// ---------------------------------------------------------------------------
// Pass B3: per-block 512-element exclusive scan + block offset -> cur8
// ---------------------------------------------------------------------------
__global__ __launch_bounds__(256) void scan_final_kernel(
    const int* __restrict__ deg, const int* __restrict__ boff,
    int* __restrict__ cur, int total) {
  __shared__ int ts[256];
  int t = threadIdx.x;
  int base = blockIdx.x * 512 + 2 * t;
  int e0 = (base < total) ? deg[base] : 0;
  int e1 = (base + 1 < total) ? deg[base + 1] : 0;
  ts[t] = e0 + e1;
  __syncthreads();
  for (int off = 1; off < 256; off <<= 1) {
    int x = (t >= off) ? ts[t - off] : 0;
    __syncthreads();
    ts[t] += x;
    __syncthreads();
  }
  int excl = ((t > 0) ? ts[t - 1] : 0) + boff[blockIdx.x];
  if (base < total) cur[base] = excl;
  if (base + 1 < total) cur[base + 1] = excl + e0;
}

// ---------------------------------------------------------------------------
// Pass C: scatter edges into the (bid&7) plane's buckets.  Atomics and
// record lines are XCD-local (no cross-XCD line bounce).  Atomics issued
// 4-deep before the dependent stores.
// ---------------------------------------------------------------------------
__global__ __launch_bounds__(256) void scatter_kernel(
    const float* __restrict__ alpha, const float* __restrict__ ew,
    const int* __restrict__ node_id, const int* __restrict__ esrc,
    const int* __restrict__ edst, int* __restrict__ cur8,
    int2* __restrict__ recs, int E, int gene_num, int N) {
  int plane = (blockIdx.x & (NXCD - 1)) * N;
  int i = (blockIdx.x * blockDim.x + threadIdx.x) * 4;
  if (i >= E) return;
  if (i + 4 <= E) {
    int4 s4 = *(const int4*)(esrc + i);
    int4 d4 = *(const int4*)(edst + i);
    float4 w4 = *(const float4*)(ew + i);
    int ss[4] = {s4.x, s4.y, s4.z, s4.w};
    int dd[4] = {d4.x, d4.y, d4.z, d4.w};
    float ww[4] = {w4.x, w4.y, w4.z, w4.w};
    float cf[4];
#pragma unroll
    for (int k = 0; k < 4; ++k) {
      int sid = node_id[ss[k]];
      int did = node_id[dd[k]];
      int idx;
      if (sid >= 0) idx = (did >= 0) ? gene_num : sid;
      else          idx = (did >= 0) ? did : (gene_num + 1);
      cf[k] = alpha[idx] * ww[k];
    }
    int pos[4];
#pragma unroll
    for (int k = 0; k < 4; ++k) pos[k] = atomicAdd(cur8 + plane + dd[k], 1);
#pragma unroll
    for (int k = 0; k < 4; ++k)
      recs[pos[k]] = make_int2(ss[k], __float_as_int(cf[k]));
  } else {
    for (int k = i; k < E; ++k) {
      int src = esrc[k], dst = edst[k];
      int sid = node_id[src], did = node_id[dst];
      int idx;
      if (sid >= 0) idx = (did >= 0) ? gene_num : sid;
      else          idx = (did >= 0) ? did : (gene_num + 1);
      float coeff = alpha[idx] * ew[k];
      int pos = atomicAdd(cur8 + plane + dst, 1);
      recs[pos] = make_int2(src, __float_as_int(coeff));
    }
  }
}

// ---------------------------------------------------------------------------
// Pass D: one wave per dst node.  Lane l owns bf16 pair (dims 2l,2l+1).
// The 8 per-XCD sub-buckets are FLATTENED into one logical record stream:
// broadcast the 8 (start,len) descriptors once, keep the exclusive cumsum in
// scalar registers (c1..c7), and map global slot j -> record index with a
// 7-compare select chain (idx = j + dsel).  One 64-wide load round then
// covers all planes (deg ~20 avg).  8-deep gather pipeline, f32 accumulate,
// mean row written once to d_out.
// ---------------------------------------------------------------------------
__global__ __launch_bounds__(256) void accumulate_kernel(
    const unsigned short* __restrict__ h16, const int2* __restrict__ recs,
    const int* __restrict__ cur8, const int* __restrict__ deg8,
    float* __restrict__ neigh, int N) {
  int wid = (blockIdx.x * blockDim.x + threadIdx.x) >> 6;
  int l = threadIdx.x & 63;
  if (wid >= N) return;
  int endv = 0, lenv = 0;
  if (l < NXCD) {
    endv = cur8[l * N + wid];   // after scatter: start + len
    lenv = deg8[l * N + wid];
  }
  int startv = endv - lenv;

  // broadcast plane descriptors (compile-time lane indices -> registers)
  int le0 = __shfl(lenv, 0), le1 = __shfl(lenv, 1), le2 = __shfl(lenv, 2),
      le3 = __shfl(lenv, 3), le4 = __shfl(lenv, 4), le5 = __shfl(lenv, 5),
      le6 = __shfl(lenv, 6), le7 = __shfl(lenv, 7);
  int s0 = __shfl(startv, 0), s1 = __shfl(startv, 1), s2 = __shfl(startv, 2),
      s3 = __shfl(startv, 3), s4 = __shfl(startv, 4), s5 = __shfl(startv, 5),
      s6 = __shfl(startv, 6), s7 = __shfl(startv, 7);
  int c1 = le0, c2 = c1 + le1, c3 = c2 + le2, c4 = c3 + le3;
  int c5 = c4 + le4, c6 = c5 + le5, c7 = c6 + le6;
  int deg_tot = c7 + le7;
  int d0 = s0, d1 = s1 - c1, d2 = s2 - c2, d3 = s3 - c3;
  int d4 = s4 - c4, d5 = s5 - c5, d6 = s6 - c6, d7 = s7 - c7;

  float ax = 0.f, ay = 0.f;
  const unsigned int* hp = ((const unsigned int*)h16) + l;  // row = 64 uints

  for (int base = 0; base < deg_tot; base += 64) {
    int j = base + l;
    int2 r = make_int2(0, 0);
    if (j < deg_tot) {
      int dsel = d0;
      dsel = (j >= c1) ? d1 : dsel;
      dsel = (j >= c2) ? d2 : dsel;
      dsel = (j >= c3) ? d3 : dsel;
      dsel = (j >= c4) ? d4 : dsel;
      dsel = (j >= c5) ? d5 : dsel;
      dsel = (j >= c6) ? d6 : dsel;
      dsel = (j >= c7) ? d7 : dsel;
      r = recs[j + dsel];
    }
    int m = deg_tot - base;
    if (m > 64) m = 64;
    int k = 0;
    for (; k + 8 <= m; k += 8) {
      int ss[8]; float cc[8]; unsigned int vv[8];
#pragma unroll
      for (int q = 0; q < 8; ++q) {
        ss[q] = __shfl(r.x, k + q);
        cc[q] = __int_as_float(__shfl(r.y, k + q));
      }
#pragma unroll
      for (int q = 0; q < 8; ++q) vv[q] = hp[(size_t)ss[q] * 64];
#pragma unroll
      for (int q = 0; q < 8; ++q) {
        ax += cc[q] * __uint_as_float(vv[q] << 16);
        ay += cc[q] * __uint_as_float(vv[q] & 0xffff0000u);
      }
    }
    for (; k + 4 <= m; k += 4) {
      int ss[4]; float cc[4]; unsigned int vv[4];
#pragma unroll
      for (int q = 0; q < 4; ++q) {
        ss[q] = __shfl(r.x, k + q);
        cc[q] = __int_as_float(__shfl(r.y, k + q));
      }
#pragma unroll
      for (int q = 0; q < 4; ++q) vv[q] = hp[(size_t)ss[q] * 64];
#pragma unroll
      for (int q = 0; q < 4; ++q) {
        ax += cc[q] * __uint_as_float(vv[q] << 16);
        ay += cc[q] * __uint_as_float(vv[q] & 0xffff0000u);
      }
    }
    for (; k < m; ++k) {
      int sv = __shfl(r.x, k);
      float cf = __int_as_float(__shfl(r.y, k));
      unsigned int v = hp[(size_t)sv * 64];
      ax += cf * __uint_as_float(v << 16);
      ay += cf * __uint_as_float(v & 0xffff0000u);
    }
  }
  float inv = 1.0f / (float)(deg_tot > 0 ? deg_tot : 1);
  ((float2*)neigh)[(size_t)wid * (D / 2) + l] = make_float2(ax * inv, ay * inv);
}

// ---------------------------------------------------------------------------
// MLP (MFMA): io = relu(io @ W.T + b), in place on d_out.  (unchanged)
// ---------------------------------------------------------------------------
__global__ __launch_bounds__(256) void mlp_mfma_kernel(
    const float* __restrict__ W, const float* __restrict__ bias,
    float* __restrict__ io, int N) {
  __shared__ __align__(16) unsigned short Wl[128 * 128];  // 32 KB bf16

  int t = threadIdx.x;
#pragma unroll
  for (int i = 0; i < 8; ++i) {
    int chunk = t + 256 * i;
    int row = chunk >> 4;
    int cb = chunk & 15;
    const float* gp = W + (size_t)row * 128 + cb * 8;
    float4 a = *(const float4*)gp;
    float4 b = *(const float4*)(gp + 4);
    bf16x8 v;
    v[0] = (short)f2bf(a.x); v[1] = (short)f2bf(a.y);
    v[2] = (short)f2bf(a.z); v[3] = (short)f2bf(a.w);
    v[4] = (short)f2bf(b.x); v[5] = (short)f2bf(b.y);
    v[6] = (short)f2bf(b.z); v[7] = (short)f2bf(b.w);
    *(bf16x8*)((char*)Wl + row * 256 + ((cb ^ (row & 7)) << 4)) = v;
  }
  __syncthreads();

  int l = t & 63;
  int w = t >> 6;
  int kg = l >> 4;
  int m_base = blockIdx.x * 64 + w * 16;
  int arow = m_base + (l & 15);
  if (arow >= N) arow = N - 1;

  bf16x8 af[4];
  const float* ap = io + (size_t)arow * 128 + kg * 8;
#pragma unroll
  for (int kk = 0; kk < 4; ++kk) {
    float4 a = *(const float4*)(ap + kk * 32);
    float4 b = *(const float4*)(ap + kk * 32 + 4);
    bf16x8 v;
    v[0] = (short)f2bf(a.x); v[1] = (short)f2bf(a.y);
    v[2] = (short)f2bf(a.z); v[3] = (short)f2bf(a.w);
    v[4] = (short)f2bf(b.x); v[5] = (short)f2bf(b.y);
    v[6] = (short)f2bf(b.z); v[7] = (short)f2bf(b.w);
    af[kk] = v;
  }

#pragma unroll
  for (int c = 0; c < 8; ++c) {
    f32x4 acc = {0.f, 0.f, 0.f, 0.f};
    int row_w = c * 16 + (l & 15);
    int rs = row_w & 7;
#pragma unroll
    for (int kk = 0; kk < 4; ++kk) {
      int cb = kk * 4 + kg;
      bf16x8 bf = *(bf16x8*)((char*)Wl + row_w * 256 + ((cb ^ rs) << 4));
      acc = __builtin_amdgcn_mfma_f32_16x16x32_bf16(af[kk], bf, acc, 0, 0, 0);
    }
    int j = c * 16 + (l & 15);
    float bj = bias[j];
#pragma unroll
    for (int r = 0; r < 4; ++r) {
      int m = m_base + kg * 4 + r;
      if (m < N) io[(size_t)m * 128 + j] = fmaxf(acc[r] + bj, 0.0f);
    }
  }
}

extern "C" void kernel_launch(void* const* d_in, const int* in_sizes, int n_in,
                              void* d_out, int out_size, void* d_ws, size_t ws_size,
                              hipStream_t stream) {
  const float* h     = (const float*)d_in[0];
  const float* alpha = (const float*)d_in[1];
  const float* ew    = (const float*)d_in[2];
  const float* W     = (const float*)d_in[3];
  const float* bias  = (const float*)d_in[4];
  const int* node_id = (const int*)d_in[5];
  const int* esrc    = (const int*)d_in[6];
  const int* edst    = (const int*)d_in[7];
  float* out = (float*)d_out;

  int E = in_sizes[2];
  int N = in_sizes[5];
  int gene_num = in_sizes[1] - 2;
  int total8 = NXCD * N;                 // 400K counters
  int nbs = (total8 + 511) / 512;        // scan blocks (<=1024)

  // workspace layout
  int* deg8 = (int*)d_ws;                       // 8N
  int* cur8 = deg8 + total8;                    // 8N
  int* bsum = cur8 + total8;                    // 1024
  int* boff = bsum + 1024;                      // 1024
  size_t h16_off = (((size_t)(2 * total8) + 2048) * sizeof(int) + 15) & ~(size_t)15;
  unsigned short* h16 = (unsigned short*)((char*)d_ws + h16_off);  // N*D bf16
  size_t rec_off = (h16_off + (size_t)N * D * sizeof(unsigned short) + 15) & ~(size_t)15;
  int2* recs = (int2*)((char*)d_ws + rec_off);  // E * 8B
  size_t need = rec_off + (size_t)E * sizeof(int2);
  if (ws_size < need) return;

  hipMemsetAsync(deg8, 0, (size_t)total8 * sizeof(int), stream);

  {
    int total4 = N * D / 4;
    cvt_kernel<<<(total4 + 255) / 256, 256, 0, stream>>>(h, h16, total4);
  }
  int eblocks = (E / 4 + 255) / 256 + 1;   // MUST match between hist & scatter
  hist_kernel<<<eblocks, 256, 0, stream>>>(edst, deg8, E, N);
  scan_reduce_kernel<<<nbs, 256, 0, stream>>>(deg8, bsum, total8);
  scan_blocksums_kernel<<<1, 1024, 0, stream>>>(bsum, boff, nbs);
  scan_final_kernel<<<nbs, 256, 0, stream>>>(deg8, boff, cur8, total8);
  scatter_kernel<<<eblocks, 256, 0, stream>>>(alpha, ew, node_id, esrc, edst,
                                              cur8, recs, E, gene_num, N);
  {
    long long total = (long long)N * 64;
    int blocks = (int)((total + 255) / 256);
    accumulate_kernel<<<blocks, 256, 0, stream>>>(h16, recs, cur8, deg8, out, N);
  }
  {
    int blocks = (N + 63) / 64;
    mlp_mfma_kernel<<<blocks, 256, 0, stream>>>(W, bias, out, N);
  }
}

// Round 8
// 116.952 us; speedup vs baseline: 1.6546x; 1.4110x over previous
//
#include <hip/hip_runtime.h>

#define D 128
#define PSHIFT 7
#define PSIZE 128            // dsts per partition
#define EDGES_PER_BLK 4096   // bin kernels: 512 thr x 8 edges
#define CAP 4608             // max records staged per partition (9*512)

typedef __attribute__((ext_vector_type(8))) short bf16x8;
typedef __attribute__((ext_vector_type(4))) float f32x4;

__device__ __forceinline__ unsigned short f2bf(float f) {
  unsigned int u = __float_as_uint(f);
  u = (u + 0x7fffu + ((u >> 16) & 1)) >> 16;
  return (unsigned short)u;
}

// ---------------------------------------------------------------------------
// Pass 0: convert h (f32) -> h16 (bf16, RNE).  4 elements / thread.
// ---------------------------------------------------------------------------
__global__ __launch_bounds__(256) void cvt_kernel(
    const float* __restrict__ h, unsigned short* __restrict__ h16, int total4) {
  int i = blockIdx.x * blockDim.x + threadIdx.x;
  if (i >= total4) return;
  float4 v = ((const float4*)h)[i];
  ushort4 o;
  o.x = f2bf(v.x); o.y = f2bf(v.y); o.z = f2bf(v.z); o.w = f2bf(v.w);
  ((ushort4*)h16)[i] = o;
}

// ---------------------------------------------------------------------------
// Pass A: partition histogram.  Block LDS-hist of 4096 edges (512 bins),
// then one global atomicAdd per nonzero bin.
// ---------------------------------------------------------------------------
__global__ __launch_bounds__(512) void bin_hist_kernel(
    const int* __restrict__ edst, int* __restrict__ g_hist, int E) {
  __shared__ int cnt[512];
  int t = threadIdx.x;
  cnt[t] = 0;
  __syncthreads();
  int eb = blockIdx.x * EDGES_PER_BLK;
#pragma unroll
  for (int q = 0; q < 8; ++q) {
    int e = eb + q * 512 + t;
    if (e < E) atomicAdd(&cnt[edst[e] >> PSHIFT], 1);
  }
  __syncthreads();
  int c = cnt[t];
  if (c > 0) atomicAdd(&g_hist[t], c);
}

// ---------------------------------------------------------------------------
// Pass B: single-block scan of 512 partition counts -> part_off (excl, +end)
// and g_cursor (running allocator for bin_scatter).
// ---------------------------------------------------------------------------
__global__ __launch_bounds__(512) void part_scan_kernel(
    const int* __restrict__ g_hist, int* __restrict__ part_off,
    int* __restrict__ g_cursor, int E) {
  __shared__ int ts[512];
  int t = threadIdx.x;
  int v = g_hist[t];
  ts[t] = v;
  __syncthreads();
  for (int off = 1; off < 512; off <<= 1) {
    int x = (t >= off) ? ts[t - off] : 0;
    __syncthreads();
    ts[t] += x;
    __syncthreads();
  }
  int excl = ts[t] - v;
  part_off[t] = excl;
  g_cursor[t] = excl;
  if (t == 0) part_off[512] = E;
}

// ---------------------------------------------------------------------------
// Pass C: LDS-binned scatter.  Per block: load 4096 edges, compute coeff,
// counting-sort into LDS by partition (atomic-rank trick), reserve global
// runs with ONE atomic per bin, write coalesced runs.
// Record: {src | (dst&127)<<16, coeff}.
// ---------------------------------------------------------------------------
__global__ __launch_bounds__(512) void bin_scatter_kernel(
    const float* __restrict__ alpha, const float* __restrict__ ew,
    const int* __restrict__ node_id, const int* __restrict__ esrc,
    const int* __restrict__ edst, int* __restrict__ g_cursor,
    int2* __restrict__ recs, int E, int gene_num) {
  __shared__ int2 lrec[EDGES_PER_BLK];            // 32 KB
  __shared__ unsigned short lbin[EDGES_PER_BLK];  // 8 KB
  __shared__ int cnt[512], offl[512], gbase[512]; // 6 KB

  int t = threadIdx.x;
  cnt[t] = 0;
  __syncthreads();

  int eb = blockIdx.x * EDGES_PER_BLK;
  int rx[8]; float rc[8]; int rb[8]; int rk[8];
#pragma unroll
  for (int q = 0; q < 8; ++q) {
    int e = eb + q * 512 + t;
    rk[q] = -1;
    if (e < E) {
      int src = esrc[e];
      int dst = edst[e];
      int sid = node_id[src];
      int did = node_id[dst];
      int idx;
      if (sid >= 0) idx = (did >= 0) ? gene_num : sid;
      else          idx = (did >= 0) ? did : (gene_num + 1);
      rc[q] = alpha[idx] * ew[e];
      rx[q] = src | ((dst & (PSIZE - 1)) << 16);
      int b = dst >> PSHIFT;
      rb[q] = b;
      rk[q] = atomicAdd(&cnt[b], 1);
    }
  }
  __syncthreads();

  // scan 512 bins (Hillis-Steele) -> offl = exclusive
  {
    int v = cnt[t];
    offl[t] = v;
    __syncthreads();
    for (int off = 1; off < 512; off <<= 1) {
      int x = (t >= off) ? offl[t - off] : 0;
      __syncthreads();
      offl[t] += x;
      __syncthreads();
    }
    int incl = offl[t];
    __syncthreads();
    offl[t] = incl - v;
  }
  __syncthreads();

  // place into LDS
#pragma unroll
  for (int q = 0; q < 8; ++q) {
    if (rk[q] >= 0) {
      int ls = offl[rb[q]] + rk[q];
      lrec[ls] = make_int2(rx[q], __float_as_int(rc[q]));
      lbin[ls] = (unsigned short)rb[q];
    }
  }
  __syncthreads();

  // reserve global runs (one atomic per nonzero bin)
  {
    int c = cnt[t];
    if (c > 0) gbase[t] = atomicAdd(&g_cursor[t], c);
  }
  __syncthreads();

  // coalesced run write-out
  int tot = E - eb;
  if (tot > EDGES_PER_BLK) tot = EDGES_PER_BLK;
  for (int s = t; s < tot; s += 512) {
    int b = lbin[s];
    recs[gbase[b] + (s - offl[b])] = lrec[s];
  }
}

// ---------------------------------------------------------------------------
// Pass D: per-partition accumulate.  Block p: stage records [part_off[p],
// part_off[p+1]) to LDS (coalesced), in-LDS counting-sort by dst&127,
// then 8 waves x 16 dsts run the shfl-broadcast h16-gather walk per dst.
// Lane l owns bf16 pair (dims 2l,2l+1).  Mean row -> neigh (d_out).
// ---------------------------------------------------------------------------
__global__ __launch_bounds__(512) void part_acc_kernel(
    const unsigned short* __restrict__ h16, const int2* __restrict__ recs,
    const int* __restrict__ part_off, float* __restrict__ neigh, int N) {
  __shared__ int2 lrec[CAP];              // 36 KB
  __shared__ unsigned short perm[CAP];    // 9 KB
  __shared__ int cnt[PSIZE], offl[PSIZE];

  int t = threadIdx.x;
  int p = blockIdx.x;
  if (t < PSIZE) cnt[t] = 0;
  __syncthreads();

  int start = part_off[p];
  int R = part_off[p + 1] - start;
  if (R > CAP) R = CAP;   // statistically impossible overflow guard

  int dlq[9]; int rkq[9];
#pragma unroll
  for (int q = 0; q < 9; ++q) {
    int s = q * 512 + t;
    rkq[q] = -1;
    if (s < R) {
      int2 r = recs[start + s];
      lrec[s] = r;
      int dl = (r.x >> 16) & (PSIZE - 1);
      dlq[q] = dl;
      rkq[q] = atomicAdd(&cnt[dl], 1);
    }
  }
  __syncthreads();

  // scan 128 bins
  {
    int v = 0;
    if (t < PSIZE) { v = cnt[t]; offl[t] = v; }
    __syncthreads();
    for (int off = 1; off < PSIZE; off <<= 1) {
      int x = 0;
      if (t < PSIZE && t >= off) x = offl[t - off];
      __syncthreads();
      if (t < PSIZE) offl[t] += x;
      __syncthreads();
    }
    if (t < PSIZE) {
      int incl = offl[t];
      offl[t] = incl - v;
    }
  }
  __syncthreads();

#pragma unroll
  for (int q = 0; q < 9; ++q) {
    if (rkq[q] >= 0) perm[offl[dlq[q]] + rkq[q]] = (unsigned short)(q * 512 + t);
  }
  __syncthreads();

  int w = t >> 6;
  int l = t & 63;
  const unsigned int* hp = ((const unsigned int*)h16) + l;  // row = 64 uints

  for (int dd = 0; dd < 16; ++dd) {
    int dl = w * 16 + dd;
    int dst = p * PSIZE + dl;
    if (dst >= N) continue;
    int c = cnt[dl];
    int o = offl[dl];
    float ax = 0.f, ay = 0.f;
    for (int base = 0; base < c; base += 64) {
      int j = base + l;
      int2 r = make_int2(0, 0);
      if (j < c) r = lrec[perm[o + j]];
      int m = c - base;
      if (m > 64) m = 64;
      int k = 0;
      for (; k + 8 <= m; k += 8) {
        int ss[8]; float cc[8]; unsigned int vv[8];
#pragma unroll
        for (int q = 0; q < 8; ++q) {
          ss[q] = __shfl(r.x, k + q) & 0xffff;
          cc[q] = __int_as_float(__shfl(r.y, k + q));
        }
#pragma unroll
        for (int q = 0; q < 8; ++q) vv[q] = hp[(size_t)ss[q] * 64];
#pragma unroll
        for (int q = 0; q < 8; ++q) {
          ax += cc[q] * __uint_as_float(vv[q] << 16);
          ay += cc[q] * __uint_as_float(vv[q] & 0xffff0000u);
        }
      }
      for (; k + 4 <= m; k += 4) {
        int ss[4]; float cc[4]; unsigned int vv[4];
#pragma unroll
        for (int q = 0; q < 4; ++q) {
          ss[q] = __shfl(r.x, k + q) & 0xffff;
          cc[q] = __int_as_float(__shfl(r.y, k + q));
        }
#pragma unroll
        for (int q = 0; q < 4; ++q) vv[q] = hp[(size_t)ss[q] * 64];
#pragma unroll
        for (int q = 0; q < 4; ++q) {
          ax += cc[q] * __uint_as_float(vv[q] << 16);
          ay += cc[q] * __uint_as_float(vv[q] & 0xffff0000u);
        }
      }
      for (; k < m; ++k) {
        int sv = __shfl(r.x, k) & 0xffff;
        float cf = __int_as_float(__shfl(r.y, k));
        unsigned int v = hp[(size_t)sv * 64];
        ax += cf * __uint_as_float(v << 16);
        ay += cf * __uint_as_float(v & 0xffff0000u);
      }
    }
    float inv = 1.0f / (float)(c > 0 ? c : 1);
    ((float2*)neigh)[(size_t)dst * (D / 2) + l] = make_float2(ax * inv, ay * inv);
  }
}

// ---------------------------------------------------------------------------
// MLP (MFMA): io = relu(io @ W.T + b), in place on d_out.  (unchanged)
// ---------------------------------------------------------------------------
__global__ __launch_bounds__(256) void mlp_mfma_kernel(
    const float* __restrict__ W, const float* __restrict__ bias,
    float* __restrict__ io, int N) {
  __shared__ __align__(16) unsigned short Wl[128 * 128];  // 32 KB bf16

  int t = threadIdx.x;
#pragma unroll
  for (int i = 0; i < 8; ++i) {
    int chunk = t + 256 * i;
    int row = chunk >> 4;
    int cb = chunk & 15;
    const float* gp = W + (size_t)row * 128 + cb * 8;
    float4 a = *(const float4*)gp;
    float4 b = *(const float4*)(gp + 4);
    bf16x8 v;
    v[0] = (short)f2bf(a.x); v[1] = (short)f2bf(a.y);
    v[2] = (short)f2bf(a.z); v[3] = (short)f2bf(a.w);
    v[4] = (short)f2bf(b.x); v[5] = (short)f2bf(b.y);
    v[6] = (short)f2bf(b.z); v[7] = (short)f2bf(b.w);
    *(bf16x8*)((char*)Wl + row * 256 + ((cb ^ (row & 7)) << 4)) = v;
  }
  __syncthreads();

  int l = t & 63;
  int w = t >> 6;
  int kg = l >> 4;
  int m_base = blockIdx.x * 64 + w * 16;
  int arow = m_base + (l & 15);
  if (arow >= N) arow = N - 1;

  bf16x8 af[4];
  const float* ap = io + (size_t)arow * 128 + kg * 8;
#pragma unroll
  for (int kk = 0; kk < 4; ++kk) {
    float4 a = *(const float4*)(ap + kk * 32);
    float4 b = *(const float4*)(ap + kk * 32 + 4);
    bf16x8 v;
    v[0] = (short)f2bf(a.x); v[1] = (short)f2bf(a.y);
    v[2] = (short)f2bf(a.z); v[3] = (short)f2bf(a.w);
    v[4] = (short)f2bf(b.x); v[5] = (short)f2bf(b.y);
    v[6] = (short)f2bf(b.z); v[7] = (short)f2bf(b.w);
    af[kk] = v;
  }

#pragma unroll
  for (int c = 0; c < 8; ++c) {
    f32x4 acc = {0.f, 0.f, 0.f, 0.f};
    int row_w = c * 16 + (l & 15);
    int rs = row_w & 7;
#pragma unroll
    for (int kk = 0; kk < 4; ++kk) {
      int cb = kk * 4 + kg;
      bf16x8 bf = *(bf16x8*)((char*)Wl + row_w * 256 + ((cb ^ rs) << 4));
      acc = __builtin_amdgcn_mfma_f32_16x16x32_bf16(af[kk], bf, acc, 0, 0, 0);
    }
    int j = c * 16 + (l & 15);
    float bj = bias[j];
#pragma unroll
    for (int r = 0; r < 4; ++r) {
      int m = m_base + kg * 4 + r;
      if (m < N) io[(size_t)m * 128 + j] = fmaxf(acc[r] + bj, 0.0f);
    }
  }
}

extern "C" void kernel_launch(void* const* d_in, const int* in_sizes, int n_in,
                              void* d_out, int out_size, void* d_ws, size_t ws_size,
                              hipStream_t stream) {
  const float* h     = (const float*)d_in[0];
  const float* alpha = (const float*)d_in[1];
  const float* ew    = (const float*)d_in[2];
  const float* W     = (const float*)d_in[3];
  const float* bias  = (const float*)d_in[4];
  const int* node_id = (const int*)d_in[5];
  const int* esrc    = (const int*)d_in[6];
  const int* edst    = (const int*)d_in[7];
  float* out = (float*)d_out;

  int E = in_sizes[2];
  int N = in_sizes[5];
  int gene_num = in_sizes[1] - 2;
  int npart = (N + PSIZE - 1) / PSIZE;          // 391 (must be <= 512)
  int eblocks = (E + EDGES_PER_BLK - 1) / EDGES_PER_BLK;  // 245

  // workspace layout
  int* g_hist   = (int*)d_ws;                   // 512
  int* part_off = g_hist + 512;                 // 513
  int* g_cursor = part_off + 513;               // 512
  size_t h16_off = ((size_t)(512 + 513 + 512) * sizeof(int) + 15) & ~(size_t)15;
  unsigned short* h16 = (unsigned short*)((char*)d_ws + h16_off);  // N*D bf16
  size_t rec_off = (h16_off + (size_t)N * D * sizeof(unsigned short) + 15) & ~(size_t)15;
  int2* recs = (int2*)((char*)d_ws + rec_off);  // E * 8B
  size_t need = rec_off + (size_t)E * sizeof(int2);
  if (ws_size < need) return;

  hipMemsetAsync(g_hist, 0, 512 * sizeof(int), stream);

  {
    int total4 = N * D / 4;
    cvt_kernel<<<(total4 + 255) / 256, 256, 0, stream>>>(h, h16, total4);
  }
  bin_hist_kernel<<<eblocks, 512, 0, stream>>>(edst, g_hist, E);
  part_scan_kernel<<<1, 512, 0, stream>>>(g_hist, part_off, g_cursor, E);
  bin_scatter_kernel<<<eblocks, 512, 0, stream>>>(alpha, ew, node_id, esrc,
                                                  edst, g_cursor, recs, E,
                                                  gene_num);
  part_acc_kernel<<<npart, 512, 0, stream>>>(h16, recs, part_off, out, N);
  {
    int blocks = (N + 63) / 64;
    mlp_mfma_kernel<<<blocks, 256, 0, stream>>>(W, bias, out, N);
  }
}

// Round 9
// 113.639 us; speedup vs baseline: 1.7029x; 1.0292x over previous
//
#include <hip/hip_runtime.h>

#define D 128
#define PSHIFT 6
#define PSIZE 64             // dsts per partition
#define EDGES_PER_BLK 4096   // bin kernels: 512 thr x 8 edges
#define CAP 2048             // max records per partition (mean 1280, +21 sigma)
#define MAXPART 1024

typedef __attribute__((ext_vector_type(8))) short bf16x8;
typedef __attribute__((ext_vector_type(4))) float f32x4;

__device__ __forceinline__ unsigned short f2bf(float f) {
  unsigned int u = __float_as_uint(f);
  u = (u + 0x7fffu + ((u >> 16) & 1)) >> 16;
  return (unsigned short)u;
}

// ---------------------------------------------------------------------------
// Fused Pass 0+A: blocks [0, cvtBlocks) convert h f32->bf16; remaining
// blocks LDS-histogram 4096 edges into 1024 partition bins, then one
// global atomic per nonzero bin.
// ---------------------------------------------------------------------------
__global__ __launch_bounds__(512) void cvt_hist_kernel(
    const float* __restrict__ h, unsigned short* __restrict__ h16, int total4,
    const int* __restrict__ edst, int* __restrict__ g_hist, int E,
    int cvtBlocks) {
  if ((int)blockIdx.x < cvtBlocks) {
    int i = blockIdx.x * 512 + threadIdx.x;
    if (i >= total4) return;
    float4 v = ((const float4*)h)[i];
    ushort4 o;
    o.x = f2bf(v.x); o.y = f2bf(v.y); o.z = f2bf(v.z); o.w = f2bf(v.w);
    ((ushort4*)h16)[i] = o;
    return;
  }
  __shared__ int cnt[MAXPART];
  int t = threadIdx.x;
  cnt[t] = 0; cnt[t + 512] = 0;
  __syncthreads();
  int eb = (blockIdx.x - cvtBlocks) * EDGES_PER_BLK;
#pragma unroll
  for (int q = 0; q < 8; ++q) {
    int e = eb + q * 512 + t;
    if (e < E) atomicAdd(&cnt[edst[e] >> PSHIFT], 1);
  }
  __syncthreads();
  int c = cnt[t];
  if (c > 0) atomicAdd(&g_hist[t], c);
  c = cnt[t + 512];
  if (c > 0) atomicAdd(&g_hist[t + 512], c);
}

// ---------------------------------------------------------------------------
// Pass B: single-block pair-scan of 1024 partition counts -> part_off
// (exclusive, +end sentinel) and g_cursor (running allocator).
// ---------------------------------------------------------------------------
__global__ __launch_bounds__(512) void part_scan_kernel(
    const int* __restrict__ g_hist, int* __restrict__ part_off,
    int* __restrict__ g_cursor, int E, int npart) {
  __shared__ int ts[512];
  int t = threadIdx.x;
  int i0 = 2 * t, i1 = 2 * t + 1;
  int v0 = (i0 < npart) ? g_hist[i0] : 0;
  int v1 = (i1 < npart) ? g_hist[i1] : 0;
  ts[t] = v0 + v1;
  __syncthreads();
  for (int off = 1; off < 512; off <<= 1) {
    int x = (t >= off) ? ts[t - off] : 0;
    __syncthreads();
    ts[t] += x;
    __syncthreads();
  }
  int excl = ts[t] - (v0 + v1);
  if (i0 < npart) { part_off[i0] = excl; g_cursor[i0] = excl; }
  if (i1 < npart) { part_off[i1] = excl + v0; g_cursor[i1] = excl + v0; }
  if (t == 0) part_off[npart] = E;
}

// ---------------------------------------------------------------------------
// Pass C: LDS-binned scatter.  Per block: 4096 edges -> coeff, counting-sort
// into LDS by partition (atomic-rank), reserve global runs with ONE atomic
// per bin, write coalesced runs.  Record: {src | (dst&63)<<16, coeff}.
// ---------------------------------------------------------------------------
__global__ __launch_bounds__(512) void bin_scatter_kernel(
    const float* __restrict__ alpha, const float* __restrict__ ew,
    const int* __restrict__ node_id, const int* __restrict__ esrc,
    const int* __restrict__ edst, int* __restrict__ g_cursor,
    int2* __restrict__ recs, int E, int gene_num) {
  __shared__ int2 lrec[EDGES_PER_BLK];            // 32 KB
  __shared__ unsigned short lbin[EDGES_PER_BLK];  // 8 KB
  __shared__ int cnt[MAXPART], offl[MAXPART], gbase[MAXPART];  // 12 KB
  __shared__ int ts[512];

  int t = threadIdx.x;
  cnt[t] = 0; cnt[t + 512] = 0;
  __syncthreads();

  int eb = blockIdx.x * EDGES_PER_BLK;
  int rx[8]; float rc[8]; int rb[8]; int rk[8];
#pragma unroll
  for (int q = 0; q < 8; ++q) {
    int e = eb + q * 512 + t;
    rk[q] = -1;
    if (e < E) {
      int src = esrc[e];
      int dst = edst[e];
      int sid = node_id[src];
      int did = node_id[dst];
      int idx;
      if (sid >= 0) idx = (did >= 0) ? gene_num : sid;
      else          idx = (did >= 0) ? did : (gene_num + 1);
      rc[q] = alpha[idx] * ew[e];
      rx[q] = src | ((dst & (PSIZE - 1)) << 16);
      int b = dst >> PSHIFT;
      rb[q] = b;
      rk[q] = atomicAdd(&cnt[b], 1);
    }
  }
  __syncthreads();

  // pair-scan of 1024 bins -> offl exclusive
  int c0 = cnt[2 * t], c1 = cnt[2 * t + 1];
  ts[t] = c0 + c1;
  __syncthreads();
  for (int off = 1; off < 512; off <<= 1) {
    int x = (t >= off) ? ts[t - off] : 0;
    __syncthreads();
    ts[t] += x;
    __syncthreads();
  }
  int exclp = ts[t] - (c0 + c1);
  offl[2 * t] = exclp;
  offl[2 * t + 1] = exclp + c0;
  __syncthreads();

  // place into LDS (sorted by bin)
#pragma unroll
  for (int q = 0; q < 8; ++q) {
    if (rk[q] >= 0) {
      int ls = offl[rb[q]] + rk[q];
      lrec[ls] = make_int2(rx[q], __float_as_int(rc[q]));
      lbin[ls] = (unsigned short)rb[q];
    }
  }
  __syncthreads();

  // reserve global runs (one atomic per nonzero bin)
  {
    int c = cnt[t];
    if (c > 0) gbase[t] = atomicAdd(&g_cursor[t], c);
    c = cnt[t + 512];
    if (c > 0) gbase[t + 512] = atomicAdd(&g_cursor[t + 512], c);
  }
  __syncthreads();

  // coalesced run write-out
  int tot = E - eb;
  if (tot > EDGES_PER_BLK) tot = EDGES_PER_BLK;
  for (int s = t; s < tot; s += 512) {
    int b = lbin[s];
    recs[gbase[b] + (s - offl[b])] = lrec[s];
  }
}

// ---------------------------------------------------------------------------
// Pass D: per-partition accumulate (64 dsts/block, 8 waves x 8 dsts).
// Stage records to LDS counting-sorted by dst&63 (direct placement, no perm
// indirection), then per-dst shfl-broadcast h16-gather walk (8-deep load
// pipeline).  Lane l owns bf16 pair (dims 2l,2l+1).  Mean row -> d_out.
// ---------------------------------------------------------------------------
__global__ __launch_bounds__(512) void part_acc_kernel(
    const unsigned short* __restrict__ h16, const int2* __restrict__ recs,
    const int* __restrict__ part_off, float* __restrict__ neigh, int N) {
  __shared__ int2 lrec[CAP];              // 16 KB, sorted by dst-low
  __shared__ int cnt[PSIZE], offl[PSIZE];

  int t = threadIdx.x;
  int p = blockIdx.x;
  if (t < PSIZE) cnt[t] = 0;
  __syncthreads();

  int start = part_off[p];
  int R = part_off[p + 1] - start;
  if (R > CAP) R = CAP;   // statistically impossible overflow guard

  int2 rq[4]; int dlq[4]; int rkq[4];
#pragma unroll
  for (int q = 0; q < 4; ++q) {
    int s = q * 512 + t;
    rkq[q] = -1;
    if (s < R) {
      int2 r = recs[start + s];
      rq[q] = r;
      int dl = (r.x >> 16) & (PSIZE - 1);
      dlq[q] = dl;
      rkq[q] = atomicAdd(&cnt[dl], 1);
    }
  }
  __syncthreads();

  // scan 64 bins
  if (t < PSIZE) offl[t] = cnt[t];
  __syncthreads();
  for (int off = 1; off < PSIZE; off <<= 1) {
    int x = 0;
    if (t < PSIZE && t >= off) x = offl[t - off];
    __syncthreads();
    if (t < PSIZE) offl[t] += x;
    __syncthreads();
  }
  if (t < PSIZE) offl[t] -= cnt[t];
  __syncthreads();

#pragma unroll
  for (int q = 0; q < 4; ++q)
    if (rkq[q] >= 0) lrec[offl[dlq[q]] + rkq[q]] = rq[q];
  __syncthreads();

  int w = t >> 6;
  int l = t & 63;
  const unsigned int* hp = ((const unsigned int*)h16) + l;  // row = 64 uints

  for (int dd = 0; dd < 8; ++dd) {
    int dl = w * 8 + dd;
    int dst = p * PSIZE + dl;
    if (dst >= N) continue;
    int c = cnt[dl];
    int o = offl[dl];
    float ax = 0.f, ay = 0.f;
    for (int base = 0; base < c; base += 64) {
      int j = base + l;
      int2 r = make_int2(0, 0);
      if (j < c) r = lrec[o + j];
      int m = c - base;
      if (m > 64) m = 64;
      int k = 0;
      for (; k + 8 <= m; k += 8) {
        int ss[8]; float cc[8]; unsigned int vv[8];
#pragma unroll
        for (int q = 0; q < 8; ++q) {
          ss[q] = __shfl(r.x, k + q) & 0xffff;
          cc[q] = __int_as_float(__shfl(r.y, k + q));
        }
#pragma unroll
        for (int q = 0; q < 8; ++q) vv[q] = hp[(size_t)ss[q] * 64];
#pragma unroll
        for (int q = 0; q < 8; ++q) {
          ax += cc[q] * __uint_as_float(vv[q] << 16);
          ay += cc[q] * __uint_as_float(vv[q] & 0xffff0000u);
        }
      }
      for (; k + 4 <= m; k += 4) {
        int ss[4]; float cc[4]; unsigned int vv[4];
#pragma unroll
        for (int q = 0; q < 4; ++q) {
          ss[q] = __shfl(r.x, k + q) & 0xffff;
          cc[q] = __int_as_float(__shfl(r.y, k + q));
        }
#pragma unroll
        for (int q = 0; q < 4; ++q) vv[q] = hp[(size_t)ss[q] * 64];
#pragma unroll
        for (int q = 0; q < 4; ++q) {
          ax += cc[q] * __uint_as_float(vv[q] << 16);
          ay += cc[q] * __uint_as_float(vv[q] & 0xffff0000u);
        }
      }
      for (; k < m; ++k) {
        int sv = __shfl(r.x, k) & 0xffff;
        float cf = __int_as_float(__shfl(r.y, k));
        unsigned int v = hp[(size_t)sv * 64];
        ax += cf * __uint_as_float(v << 16);
        ay += cf * __uint_as_float(v & 0xffff0000u);
      }
    }
    float inv = 1.0f / (float)(c > 0 ? c : 1);
    ((float2*)neigh)[(size_t)dst * (D / 2) + l] = make_float2(ax * inv, ay * inv);
  }
}

// ---------------------------------------------------------------------------
// MLP (MFMA): io = relu(io @ W.T + b), in place on d_out.  (unchanged)
// ---------------------------------------------------------------------------
__global__ __launch_bounds__(256) void mlp_mfma_kernel(
    const float* __restrict__ W, const float* __restrict__ bias,
    float* __restrict__ io, int N) {
  __shared__ __align__(16) unsigned short Wl[128 * 128];  // 32 KB bf16

  int t = threadIdx.x;
#pragma unroll
  for (int i = 0; i < 8; ++i) {
    int chunk = t + 256 * i;
    int row = chunk >> 4;
    int cb = chunk & 15;
    const float* gp = W + (size_t)row * 128 + cb * 8;
    float4 a = *(const float4*)gp;
    float4 b = *(const float4*)(gp + 4);
    bf16x8 v;
    v[0] = (short)f2bf(a.x); v[1] = (short)f2bf(a.y);
    v[2] = (short)f2bf(a.z); v[3] = (short)f2bf(a.w);
    v[4] = (short)f2bf(b.x); v[5] = (short)f2bf(b.y);
    v[6] = (short)f2bf(b.z); v[7] = (short)f2bf(b.w);
    *(bf16x8*)((char*)Wl + row * 256 + ((cb ^ (row & 7)) << 4)) = v;
  }
  __syncthreads();

  int l = t & 63;
  int w = t >> 6;
  int kg = l >> 4;
  int m_base = blockIdx.x * 64 + w * 16;
  int arow = m_base + (l & 15);
  if (arow >= N) arow = N - 1;

  bf16x8 af[4];
  const float* ap = io + (size_t)arow * 128 + kg * 8;
#pragma unroll
  for (int kk = 0; kk < 4; ++kk) {
    float4 a = *(const float4*)(ap + kk * 32);
    float4 b = *(const float4*)(ap + kk * 32 + 4);
    bf16x8 v;
    v[0] = (short)f2bf(a.x); v[1] = (short)f2bf(a.y);
    v[2] = (short)f2bf(a.z); v[3] = (short)f2bf(a.w);
    v[4] = (short)f2bf(b.x); v[5] = (short)f2bf(b.y);
    v[6] = (short)f2bf(b.z); v[7] = (short)f2bf(b.w);
    af[kk] = v;
  }

#pragma unroll
  for (int c = 0; c < 8; ++c) {
    f32x4 acc = {0.f, 0.f, 0.f, 0.f};
    int row_w = c * 16 + (l & 15);
    int rs = row_w & 7;
#pragma unroll
    for (int kk = 0; kk < 4; ++kk) {
      int cb = kk * 4 + kg;
      bf16x8 bf = *(bf16x8*)((char*)Wl + row_w * 256 + ((cb ^ rs) << 4));
      acc = __builtin_amdgcn_mfma_f32_16x16x32_bf16(af[kk], bf, acc, 0, 0, 0);
    }
    int j = c * 16 + (l & 15);
    float bj = bias[j];
#pragma unroll
    for (int r = 0; r < 4; ++r) {
      int m = m_base + kg * 4 + r;
      if (m < N) io[(size_t)m * 128 + j] = fmaxf(acc[r] + bj, 0.0f);
    }
  }
}

extern "C" void kernel_launch(void* const* d_in, const int* in_sizes, int n_in,
                              void* d_out, int out_size, void* d_ws, size_t ws_size,
                              hipStream_t stream) {
  const float* h     = (const float*)d_in[0];
  const float* alpha = (const float*)d_in[1];
  const float* ew    = (const float*)d_in[2];
  const float* W     = (const float*)d_in[3];
  const float* bias  = (const float*)d_in[4];
  const int* node_id = (const int*)d_in[5];
  const int* esrc    = (const int*)d_in[6];
  const int* edst    = (const int*)d_in[7];
  float* out = (float*)d_out;

  int E = in_sizes[2];
  int N = in_sizes[5];
  int gene_num = in_sizes[1] - 2;
  int npart = (N + PSIZE - 1) / PSIZE;          // 782 (must be <= 1024)
  int eblocks = (E + EDGES_PER_BLK - 1) / EDGES_PER_BLK;  // 245
  int total4 = N * D / 4;
  int cvtBlocks = (total4 + 511) / 512;         // 3125

  // workspace layout
  int* g_hist   = (int*)d_ws;                   // 1024
  int* part_off = g_hist + MAXPART;             // npart+1 (<=1025)
  int* g_cursor = part_off + MAXPART + 1;       // 1024
  size_t h16_off = ((size_t)(3 * MAXPART + 1) * sizeof(int) + 15) & ~(size_t)15;
  unsigned short* h16 = (unsigned short*)((char*)d_ws + h16_off);  // N*D bf16
  size_t rec_off = (h16_off + (size_t)N * D * sizeof(unsigned short) + 15) & ~(size_t)15;
  int2* recs = (int2*)((char*)d_ws + rec_off);  // E * 8B
  size_t need = rec_off + (size_t)E * sizeof(int2);
  if (ws_size < need) return;

  hipMemsetAsync(g_hist, 0, MAXPART * sizeof(int), stream);

  cvt_hist_kernel<<<cvtBlocks + eblocks, 512, 0, stream>>>(
      h, h16, total4, edst, g_hist, E, cvtBlocks);
  part_scan_kernel<<<1, 512, 0, stream>>>(g_hist, part_off, g_cursor, E, npart);
  bin_scatter_kernel<<<eblocks, 512, 0, stream>>>(alpha, ew, node_id, esrc,
                                                  edst, g_cursor, recs, E,
                                                  gene_num);
  part_acc_kernel<<<npart, 512, 0, stream>>>(h16, recs, part_off, out, N);
  {
    int blocks = (N + 63) / 64;
    mlp_mfma_kernel<<<blocks, 256, 0, stream>>>(W, bias, out, N);
  }
}